// Round 1
// baseline (433.531 us; speedup 1.0000x reference)
//
#include <hip/hip_runtime.h>
#include <hip/hip_bf16.h>
#include <math.h>

#define N_NODES 50000
#define F 64
#define OUTF 32

// ---------------- degree: deg[src] += w ----------------
__global__ void deg_kernel(const int* __restrict__ src, const float* __restrict__ w,
                           float* __restrict__ deg, int E) {
    int e = blockIdx.x * 256 + threadIdx.x;
    if (e < E) {
        int s = src[e];
        if ((unsigned)s < N_NODES) unsafeAtomicAdd(&deg[s], w[e]);
    }
}

// ---------------- dinv = deg>0 ? rsqrt(deg) : 0 ----------------
__global__ void dinv_kernel(const float* __restrict__ deg, float* __restrict__ dinv, int n) {
    int i = blockIdx.x * 256 + threadIdx.x;
    if (i < n) {
        float d = deg[i];
        dinv[i] = d > 0.f ? rsqrtf(d) : 0.f;
    }
}

// ---------------- P[dst,:] += (-dinv[src]*w*dinv[dst]) * x[src,:] ----------------
// one wave (64 lanes) per edge; lane = feature index
__global__ void scatter_kernel(const int* __restrict__ src, const int* __restrict__ dst,
                               const float* __restrict__ w, const float* __restrict__ dinv,
                               const float* __restrict__ x, float* __restrict__ P, int E) {
    int t = blockIdx.x * 256 + threadIdx.x;
    int e = t >> 6;
    int lane = t & 63;
    if (e >= E) return;
    int s = src[e];
    int d = dst[e];
    if ((unsigned)s >= N_NODES || (unsigned)d >= N_NODES) return;
    float coef = -dinv[s] * w[e] * dinv[d];
    unsafeAtomicAdd(&P[d * F + lane], coef * x[s * F + lane]);
}

// ---------------- fused dense: gates + GRU combine + linear + L2-normalize ----------------
// z_pre = [x;P] @ [Wxz0;Wxz1] + (bxz+bhz)
// h_pre = [x;P] @ [Wxh0;Wxh1] + (bxh+bhh)
// H = (1 - sigmoid(z_pre)) * tanh(h_pre)
// out = normalize(H @ Wlin + blin)
__launch_bounds__(256, 2)
__global__ void dense_kernel(const float* __restrict__ x, const float* __restrict__ P,
                             const float* __restrict__ Wxz0, const float* __restrict__ Wxz1,
                             const float* __restrict__ bxz, const float* __restrict__ bhz,
                             const float* __restrict__ Wxh0, const float* __restrict__ Wxh1,
                             const float* __restrict__ bxh, const float* __restrict__ bhh,
                             const float* __restrict__ Wlin, const float* __restrict__ blin,
                             float* __restrict__ out) {
    __shared__ float Wz[128 * 64];   // 32 KB
    __shared__ float Wh[128 * 64];   // 32 KB
    __shared__ float Wl[64 * 32];    // 8 KB
    __shared__ float bz[64], bh[64], bl[32];
    __shared__ float xp[4][128];
    __shared__ float Hb[4][64];

    int tid = threadIdx.x;
    for (int i = tid; i < 4096; i += 256) {
        Wz[i] = Wxz0[i]; Wz[4096 + i] = Wxz1[i];
        Wh[i] = Wxh0[i]; Wh[4096 + i] = Wxh1[i];
    }
    for (int i = tid; i < 2048; i += 256) Wl[i] = Wlin[i];
    if (tid < 64) { bz[tid] = bxz[tid] + bhz[tid]; bh[tid] = bxh[tid] + bhh[tid]; }
    if (tid < 32) bl[tid] = blin[tid];
    __syncthreads();

    int ln = tid >> 6;   // local node slot (wave id), 0..3
    int j  = tid & 63;   // feature lane

    int ngroups = (N_NODES + 3) / 4;
    for (int g = blockIdx.x; g < ngroups; g += gridDim.x) {
        int node = g * 4 + ln;
        bool valid = node < N_NODES;
        if (valid) {
            xp[ln][j]      = x[node * F + j];
            xp[ln][64 + j] = P[node * F + j];
        }
        __syncthreads();

        float zacc = bz[j], hacc = bh[j];
        #pragma unroll 16
        for (int k = 0; k < 128; ++k) {
            float a = xp[ln][k];            // LDS broadcast within wave
            zacc = fmaf(a, Wz[k * 64 + j], zacc);
            hacc = fmaf(a, Wh[k * 64 + j], hacc);
        }
        float Z  = 1.f / (1.f + __expf(-zacc));
        float Ht = tanhf(hacc);
        Hb[ln][j] = (1.f - Z) * Ht;
        __syncthreads();

        if (valid && j < 32) {
            float hm = bl[j];
            #pragma unroll
            for (int k = 0; k < 64; ++k) hm = fmaf(Hb[ln][k], Wl[k * 32 + j], hm);
            float ss = hm * hm;
            #pragma unroll
            for (int off = 16; off > 0; off >>= 1) ss += __shfl_xor(ss, off, 32);
            float denom = fmaxf(sqrtf(ss), 1e-12f);
            out[node * OUTF + j] = hm / denom;
        }
        __syncthreads();   // protect xp/Hb before next iteration overwrites
    }
}

extern "C" void kernel_launch(void* const* d_in, const int* in_sizes, int n_in,
                              void* d_out, int out_size, void* d_ws, size_t ws_size,
                              hipStream_t stream) {
    // setup_inputs order:
    // 0:x 1:edge_index 2:edge_weight
    // 3:Wxz0 4:Wxz1 5:bxz  6:Whz0 7:Whz1 8:bhz  9:Wxr0 10:Wxr1 11:bxr
    // 12:Whr0 13:Whr1 14:bhr  15:Wxh0 16:Wxh1 17:bxh  18:Whh0 19:Whh1 20:bhh
    // 21:Wlin 22:blin
    const float* x    = (const float*)d_in[0];
    const int*   ei   = (const int*)d_in[1];
    const float* ew   = (const float*)d_in[2];
    const float* Wxz0 = (const float*)d_in[3];
    const float* Wxz1 = (const float*)d_in[4];
    const float* bxz  = (const float*)d_in[5];
    const float* bhz  = (const float*)d_in[8];
    const float* Wxh0 = (const float*)d_in[15];
    const float* Wxh1 = (const float*)d_in[16];
    const float* bxh  = (const float*)d_in[17];
    const float* bhh  = (const float*)d_in[20];
    const float* Wlin = (const float*)d_in[21];
    const float* blin = (const float*)d_in[22];
    float* out = (float*)d_out;

    int E = in_sizes[2];              // edge count from edge_weight
    const int* src = ei;
    const int* dst = ei + E;

    // workspace layout: deg[N] | P[N*F] | dinv[N]
    float* deg  = (float*)d_ws;
    float* P    = deg + N_NODES;
    float* dinv = P + (size_t)N_NODES * F;

    // zero deg + P (contiguous)
    hipMemsetAsync(d_ws, 0, (size_t)(N_NODES + (size_t)N_NODES * F) * sizeof(float), stream);

    deg_kernel<<<(E + 255) / 256, 256, 0, stream>>>(src, ew, deg, E);
    dinv_kernel<<<(N_NODES + 255) / 256, 256, 0, stream>>>(deg, dinv, N_NODES);
    scatter_kernel<<<(E * 64 + 255) / 256, 256, 0, stream>>>(src, dst, ew, dinv, x, P, E);
    dense_kernel<<<512, 256, 0, stream>>>(x, P, Wxz0, Wxz1, bxz, bhz,
                                          Wxh0, Wxh1, bxh, bhh, Wlin, blin, out);
}

// Round 2
// 265.880 us; speedup vs baseline: 1.6305x; 1.6305x over previous
//
#include <hip/hip_runtime.h>
#include <math.h>

#define N_NODES 50000
#define F 64
#define OUTF 32

typedef __bf16 v8bf __attribute__((ext_vector_type(8)));
typedef float v4f __attribute__((ext_vector_type(4)));

static __device__ __forceinline__ unsigned short f2bf(float f) {
    union { float f; unsigned u; } v; v.f = f;
    unsigned r = v.u + 0x7FFFu + ((v.u >> 16) & 1u);   // round-to-nearest-even
    return (unsigned short)(r >> 16);
}
static __device__ __forceinline__ float bf2f(unsigned short h) {
    union { unsigned u; float f; } v; v.u = ((unsigned)h) << 16;
    return v.f;
}

// ---------------- cast x -> bf16 (packed pairs) ----------------
__global__ void cast_x_kernel(const float2* __restrict__ x2, unsigned int* __restrict__ xb2, int n2) {
    int i = blockIdx.x * 256 + threadIdx.x;
    if (i < n2) {
        float2 v = x2[i];
        xb2[i] = (unsigned)f2bf(v.x) | ((unsigned)f2bf(v.y) << 16);
    }
}

// ---------------- prep weights: combined transposed bf16 B matrices + biases ----------------
// Bt[n*128+k] = W[k][n] where W = [[Wxz0|Wxh0],[Wxz1|Wxh1]]  (128K x 128N)
// Wlt[n*64+k] = Wlin[k][n]
__global__ void prep_w_kernel(const float* __restrict__ Wxz0, const float* __restrict__ Wxz1,
                              const float* __restrict__ Wxh0, const float* __restrict__ Wxh1,
                              const float* __restrict__ Wlin,
                              const float* __restrict__ bxz, const float* __restrict__ bhz,
                              const float* __restrict__ bxh, const float* __restrict__ bhh,
                              const float* __restrict__ blin,
                              unsigned short* __restrict__ Bt, unsigned short* __restrict__ Wlt,
                              float* __restrict__ bzc, float* __restrict__ blc) {
    int idx = blockIdx.x * 256 + threadIdx.x;
    if (idx < 16384) {
        int k = idx & 127, n = idx >> 7;
        float v;
        if (k < 64) v = (n < 64) ? Wxz0[k * 64 + n] : Wxh0[k * 64 + (n - 64)];
        else        v = (n < 64) ? Wxz1[(k - 64) * 64 + n] : Wxh1[(k - 64) * 64 + (n - 64)];
        Bt[n * 128 + k] = f2bf(v);
    } else if (idx < 16384 + 2048) {
        int j = idx - 16384; int k = j & 63, n = j >> 6;
        Wlt[n * 64 + k] = f2bf(Wlin[k * 32 + n]);
    } else if (idx < 16384 + 2048 + 128) {
        int j = idx - 16384 - 2048;
        bzc[j] = (j < 64) ? (bxz[j] + bhz[j]) : (bxh[j - 64] + bhh[j - 64]);
    } else if (idx < 16384 + 2048 + 128 + 32) {
        int j = idx - 16384 - 2048 - 128;
        blc[j] = blin[j];
    }
}

// ---------------- degree: deg[src] += w ----------------
__global__ void deg_kernel(const int* __restrict__ src, const float* __restrict__ w,
                           float* __restrict__ deg, int E) {
    int e = blockIdx.x * 256 + threadIdx.x;
    if (e < E) {
        int s = src[e];
        if ((unsigned)s < N_NODES) unsafeAtomicAdd(&deg[s], w[e]);
    }
}

// ---------------- dinv = deg>0 ? rsqrt(deg) : 0 ----------------
__global__ void dinv_kernel(const float* __restrict__ deg, float* __restrict__ dinv, int n) {
    int i = blockIdx.x * 256 + threadIdx.x;
    if (i < n) {
        float d = deg[i];
        dinv[i] = d > 0.f ? rsqrtf(d) : 0.f;
    }
}

// ---------------- scatter: Pb[d,:] += coef * xb[s,:]  (packed bf16 atomics) ----------------
// 2 edges per wave; 32 lanes/edge; each lane handles 2 features via pk_add_bf16
__global__ void scatter_kernel(const int* __restrict__ src, const int* __restrict__ dst,
                               const float* __restrict__ w, const float* __restrict__ dinv,
                               const unsigned int* __restrict__ xb2, unsigned int* __restrict__ Pb2,
                               int E) {
    int t = blockIdx.x * 256 + threadIdx.x;
    int e = t >> 5;
    if (e >= E) return;
    int lane = t & 31;
    int s = src[e], d = dst[e];
    if ((unsigned)s >= N_NODES || (unsigned)d >= N_NODES) return;
    float coef = -dinv[s] * w[e] * dinv[d];
    unsigned xv = xb2[(size_t)s * 32 + lane];
    unsigned short lo = f2bf(coef * bf2f((unsigned short)(xv & 0xFFFFu)));
    unsigned short hi = f2bf(coef * bf2f((unsigned short)(xv >> 16)));
    unsigned packed = (unsigned)lo | ((unsigned)hi << 16);
    unsigned int* addr = Pb2 + (size_t)d * 32 + lane;
    asm volatile("global_atomic_pk_add_bf16 %0, %1, off" :: "v"(addr), "v"(packed) : "memory");
}

// ---------------- fused dense (MFMA): gates GEMM + GRU + linear + L2-normalize ----------------
// Block = 64 rows (4 waves x 16-row stripes). GEMM1: [xb|Pb](16x128) @ B(128x128) -> z|h.
// Epilogue: H=(1-sigmoid(z))*tanh(h) elementwise in C-layout regs -> LDS (bf16).
// GEMM2: H(16x64) @ Wl(64x32); row-norm via shfl; store.
__launch_bounds__(256, 3)
__global__ void dense_kernel(const unsigned short* __restrict__ xb, const unsigned short* __restrict__ Pb,
                             const unsigned short* __restrict__ Bt, const unsigned short* __restrict__ Wlt,
                             const float* __restrict__ bzc, const float* __restrict__ blc,
                             float* __restrict__ out) {
    __shared__ unsigned short Bs[128 * 136];   // stride 136: 16B-aligned b128 reads, 2-way banks (free)
    __shared__ unsigned short Wls[32 * 80];
    __shared__ unsigned short Hs[4][16 * 80];  // per-wave H stripe, stride 80 (16B aligned)
    __shared__ float bzs[128], bls[32];

    int tid = threadIdx.x;
    for (int c = tid; c < 4096; c += 256) {            // B: 4-bf16 (8B) chunks
        int n = c >> 5; int k4 = (c & 31) * 4;
        *(uint2*)&Bs[n * 136 + k4] = *(const uint2*)&Bt[n * 128 + k4];
    }
    for (int c = tid; c < 512; c += 256) {
        int n = c >> 4; int k4 = (c & 15) * 4;
        *(uint2*)&Wls[n * 80 + k4] = *(const uint2*)&Wlt[n * 64 + k4];
    }
    if (tid < 128) bzs[tid] = bzc[tid];
    if (tid < 32) bls[tid] = blc[tid];
    __syncthreads();

    int wv = tid >> 6, lane = tid & 63;
    int nl = lane & 15, q = lane >> 4;
    int rowbase = blockIdx.x * 64 + wv * 16;

    // ---- GEMM1 ----
    int arow = rowbase + nl; if (arow >= N_NODES) arow = N_NODES - 1;
    v4f acc[8];
    #pragma unroll
    for (int i = 0; i < 8; ++i) acc[i] = (v4f)(0.f);

    #pragma unroll
    for (int kk = 0; kk < 4; ++kk) {
        int k0 = kk * 32 + q * 8;
        const unsigned short* ap = (kk < 2) ? (xb + (size_t)arow * 64 + k0)
                                            : (Pb + (size_t)arow * 64 + (k0 - 64));
        v8bf a = *(const v8bf*)ap;
        #pragma unroll
        for (int tn = 0; tn < 8; ++tn) {
            v8bf b = *(const v8bf*)&Bs[(tn * 16 + nl) * 136 + kk * 32 + q * 8];
            acc[tn] = __builtin_amdgcn_mfma_f32_16x16x32_bf16(a, b, acc[tn], 0, 0, 0);
        }
    }

    // ---- epilogue 1: H = (1-sigmoid(z))*tanh(h) ----
    #pragma unroll
    for (int tn = 0; tn < 4; ++tn) {
        int n = tn * 16 + nl;
        float bz = bzs[n], bh = bzs[64 + n];
        #pragma unroll
        for (int r = 0; r < 4; ++r) {
            float z = acc[tn][r] + bz;
            float h = acc[tn + 4][r] + bh;
            float sg = 1.f / (1.f + __expf(-z));
            float th = 1.f - 2.f / (__expf(2.f * h) + 1.f);
            int m = q * 4 + r;
            Hs[wv][m * 80 + n] = f2bf((1.f - sg) * th);
        }
    }
    // Hs[wv] is wave-private: compiler's lgkmcnt waits order write->read, no barrier needed

    // ---- GEMM2 ----
    v4f acc2[2];
    acc2[0] = (v4f)(0.f); acc2[1] = (v4f)(0.f);
    #pragma unroll
    for (int kk = 0; kk < 2; ++kk) {
        v8bf a = *(const v8bf*)&Hs[wv][nl * 80 + kk * 32 + q * 8];
        #pragma unroll
        for (int tn = 0; tn < 2; ++tn) {
            v8bf b = *(const v8bf*)&Wls[(tn * 16 + nl) * 80 + kk * 32 + q * 8];
            acc2[tn] = __builtin_amdgcn_mfma_f32_16x16x32_bf16(a, b, acc2[tn], 0, 0, 0);
        }
    }

    // ---- epilogue 2: bias + L2 normalize + store ----
    float o0[4], o1[4];
    #pragma unroll
    for (int r = 0; r < 4; ++r) {
        o0[r] = acc2[0][r] + bls[nl];
        o1[r] = acc2[1][r] + bls[16 + nl];
    }
    #pragma unroll
    for (int r = 0; r < 4; ++r) {
        float ss = o0[r] * o0[r] + o1[r] * o1[r];
        ss += __shfl_xor(ss, 1);
        ss += __shfl_xor(ss, 2);
        ss += __shfl_xor(ss, 4);
        ss += __shfl_xor(ss, 8);
        float dn = fmaxf(sqrtf(ss), 1e-12f);
        int node = rowbase + q * 4 + r;
        if (node < N_NODES) {
            out[node * 32 + nl] = o0[r] / dn;
            out[node * 32 + 16 + nl] = o1[r] / dn;
        }
    }
}

extern "C" void kernel_launch(void* const* d_in, const int* in_sizes, int n_in,
                              void* d_out, int out_size, void* d_ws, size_t ws_size,
                              hipStream_t stream) {
    const float* x    = (const float*)d_in[0];
    const int*   ei   = (const int*)d_in[1];
    const float* ew   = (const float*)d_in[2];
    const float* Wxz0 = (const float*)d_in[3];
    const float* Wxz1 = (const float*)d_in[4];
    const float* bxz  = (const float*)d_in[5];
    const float* bhz  = (const float*)d_in[8];
    const float* Wxh0 = (const float*)d_in[15];
    const float* Wxh1 = (const float*)d_in[16];
    const float* bxh  = (const float*)d_in[17];
    const float* bhh  = (const float*)d_in[20];
    const float* Wlin = (const float*)d_in[21];
    const float* blin = (const float*)d_in[22];
    float* out = (float*)d_out;

    int E = in_sizes[2];
    const int* src = ei;
    const int* dst = ei + E;

    // workspace layout (bytes):
    // [0, 200000)              deg   (f32, zeroed)
    // [200000, 6600000)        Pb    (bf16 N*64, zeroed)
    // [6600000, 6800000)       dinv  (f32)
    // [6800000, 13200000)      xb    (bf16 N*64)
    // [13200000, 13232768)     Bt    (bf16 128*128)
    // [13232768, 13236864)     Wlt   (bf16 32*64)
    // [13236864, 13237376)     bzc   (f32 128)
    // [13237376, 13237504)     blc   (f32 32)
    char* base = (char*)d_ws;
    float*          deg  = (float*)(base + 0);
    unsigned short* Pb   = (unsigned short*)(base + 200000);
    float*          dinv = (float*)(base + 6600000);
    unsigned short* xb   = (unsigned short*)(base + 6800000);
    unsigned short* Bt   = (unsigned short*)(base + 13200000);
    unsigned short* Wlt  = (unsigned short*)(base + 13232768);
    float*          bzc  = (float*)(base + 13236864);
    float*          blc  = (float*)(base + 13237376);

    // zero deg + Pb (contiguous)
    hipMemsetAsync(base, 0, 6600000, stream);

    cast_x_kernel<<<(N_NODES * 32 + 255) / 256, 256, 0, stream>>>((const float2*)x, (unsigned int*)xb, N_NODES * 32);
    prep_w_kernel<<<(16384 + 2048 + 128 + 32 + 255) / 256, 256, 0, stream>>>(
        Wxz0, Wxz1, Wxh0, Wxh1, Wlin, bxz, bhz, bxh, bhh, blin, Bt, Wlt, bzc, blc);
    deg_kernel<<<(E + 255) / 256, 256, 0, stream>>>(src, ew, deg, E);
    dinv_kernel<<<(N_NODES + 255) / 256, 256, 0, stream>>>(deg, dinv, N_NODES);
    scatter_kernel<<<(E * 32 + 255) / 256, 256, 0, stream>>>(src, dst, ew, dinv,
                                                             (const unsigned int*)xb, (unsigned int*)Pb, E);
    dense_kernel<<<(N_NODES + 63) / 64, 256, 0, stream>>>(xb, Pb, Bt, Wlt, bzc, blc, out);
}